// Round 14
// baseline (305.831 us; speedup 1.0000x reference)
//
#include <hip/hip_runtime.h>
#include <hip/hip_bf16.h>

// EdgePredictorGNN: 2-layer GCN + edge MLP.
// N=50000 nodes, in_c=128, hid=64, out_c=16, E=800000 edges.
// Round-14: QUAD-pipelined agg gather (4 nodes/wave, 16 rows in flight),
// k_init_cnt replaced by hipMemsetAsync. Pair version measured 292.5 us;
// across-node pipelining is the confirmed lever for the latency-bound gather.

#define IN_C 128
#define HID 64
#define OUT_C 16

__device__ __forceinline__ float rlanef(float v, int l) {
    return __uint_as_float(__builtin_amdgcn_readlane(__float_as_uint(v), l));
}

// ---------------- CSR build ----------------

__global__ void k_count(const int* __restrict__ ei, int* __restrict__ cnt, int e) {
    int i = blockIdx.x * blockDim.x + threadIdx.x;
    if (i < e) atomicAdd(&cnt[ei[e + i]], 1);   // dst = ei[1][i]
}

__global__ __launch_bounds__(1024) void k_scan1(const int* __restrict__ cnt,
                                                int* __restrict__ tmp,
                                                int* __restrict__ bsum, int n) {
    __shared__ int s[1024];
    int i = blockIdx.x * 1024 + threadIdx.x;
    int v = (i < n) ? cnt[i] : 0;
    s[threadIdx.x] = v;
    __syncthreads();
    for (int off = 1; off < 1024; off <<= 1) {
        int add = (threadIdx.x >= off) ? s[threadIdx.x - off] : 0;
        __syncthreads();
        s[threadIdx.x] += add;
        __syncthreads();
    }
    if (i < n) tmp[i] = s[threadIdx.x];
    if (threadIdx.x == 1023) bsum[blockIdx.x] = s[1023];
}

// wave-parallel exclusive scan of up to 64 block sums
__global__ __launch_bounds__(64) void k_scan2(int* __restrict__ bsum, int nb) {
    int lane = threadIdx.x;
    int v = (lane < nb) ? bsum[lane] : 0;
    int orig = v;
    for (int off = 1; off < 64; off <<= 1) {
        int t = __shfl_up(v, off, 64);
        if (lane >= off) v += t;
    }
    if (lane < nb) bsum[lane] = v - orig;   // exclusive prefix
}

__global__ void k_scan3(const int* __restrict__ cnt, const int* __restrict__ tmp,
                        const int* __restrict__ bsum, int* __restrict__ rowptr,
                        int* __restrict__ cur, float* __restrict__ dinv, int n, int e) {
    int i = blockIdx.x * blockDim.x + threadIdx.x;
    if (i < n) {
        int excl = tmp[i] - cnt[i] + bsum[i >> 10];
        rowptr[i] = excl;
        cur[i] = excl;
        dinv[i] = 1.0f / sqrtf((float)(cnt[i] + 1));  // +1 self loop
        if (i == 0) rowptr[n] = e;
    }
}

__global__ void k_scatter(const int* __restrict__ ei, int* __restrict__ cur,
                          int* __restrict__ csrc, int2* __restrict__ cde, int e) {
    int i = blockIdx.x * blockDim.x + threadIdx.x;
    if (i < e) {
        int s = ei[i];
        int d = ei[e + i];
        int p = atomicAdd(&cur[d], 1);
        csrc[p] = s;
        cde[p] = make_int2(d, i);
    }
}

// ---------------- node GEMM: T = (A @ W) * dinv[row]  (W is [K,64]) ----------------

template <int K>
__global__ __launch_bounds__(256) void k_gemm_node(const float* __restrict__ A,
                                                   const float* __restrict__ W,
                                                   const float* __restrict__ dinv,
                                                   float* __restrict__ T,
                                                   int n, int npw) {
    int lane = threadIdx.x & 63;
    int w = threadIdx.x >> 6;
    float wr[K];
#pragma unroll
    for (int k = 0; k < K; ++k) wr[k] = W[k * 64 + lane];
    int gw = blockIdx.x * 4 + w;
    int n0 = gw * npw;
    int n1 = n0 + npw; if (n1 > n) n1 = n;
#pragma unroll 1
    for (int i = n0; i < n1; ++i) {
        float a0 = A[(size_t)i * K + lane];
        float a1 = 0.f;
        if (K == 128) a1 = A[(size_t)i * K + 64 + lane];
        float acc = 0.f;
#pragma unroll
        for (int k = 0; k < 64; ++k) acc = fmaf(rlanef(a0, k), wr[k], acc);
        if (K == 128) {
#pragma unroll
            for (int k = 0; k < 64; ++k) acc = fmaf(rlanef(a1, k), wr[64 + k], acc);
        }
        T[(size_t)i * 64 + lane] = acc * dinv[i];
    }
}

// ---------------- GCN aggregation, QUAD-pipelined gather core ----------------
// lane = (g = lane>>4, c4 = lane&15). Four nodes gathered concurrently:
// 4 coalesced index preloads; row loop interleaves 4 chains (16 rows in
// flight per iter). Trip counts wave-uniform; __shfl at full EXEC; only the
// adds are predicated. Per-node summation order = single-node version.

#define AGG_SELF(acc, nid) \
    acc = *(const float4*)(T + (size_t)(nid) * 64 + 4 * c4);

#define AGG_ADD(acc, s) { \
    float4 t = *(const float4*)(T + (size_t)(s) * 64 + 4 * c4); \
    acc.x += t.x; acc.y += t.y; acc.z += t.z; acc.w += t.w; }

#define AGG_REDUCE(acc, h, dn) \
    acc.x += __shfl_xor(acc.x, 16, 64); acc.y += __shfl_xor(acc.y, 16, 64); \
    acc.z += __shfl_xor(acc.z, 16, 64); acc.w += __shfl_xor(acc.w, 16, 64); \
    acc.x += __shfl_xor(acc.x, 32, 64); acc.y += __shfl_xor(acc.y, 32, 64); \
    acc.z += __shfl_xor(acc.z, 32, 64); acc.w += __shfl_xor(acc.w, 32, 64); \
    h.x = fmaxf(fmaf(dn, acc.x, b4.x), 0.f); \
    h.y = fmaxf(fmaf(dn, acc.y, b4.y), 0.f); \
    h.z = fmaxf(fmaf(dn, acc.z, b4.z), 0.f); \
    h.w = fmaxf(fmaf(dn, acc.w, b4.w), 0.f);

__device__ __forceinline__ void agg_gather4(const float* __restrict__ T,
                                            const int* __restrict__ rowptr,
                                            const int* __restrict__ csrc,
                                            float dnA, float dnB, float dnC, float dnD,
                                            float4 b4,
                                            int nidA, int nidB, int nidC, int nidD,
                                            int g, int c4, int lane,
                                            float4& hA, float4& hB,
                                            float4& hC, float4& hD) {
    float4 accA = make_float4(0.f, 0.f, 0.f, 0.f);
    float4 accB = make_float4(0.f, 0.f, 0.f, 0.f);
    float4 accC = make_float4(0.f, 0.f, 0.f, 0.f);
    float4 accD = make_float4(0.f, 0.f, 0.f, 0.f);
    if (g == 0) {
        AGG_SELF(accA, nidA)
        AGG_SELF(accB, nidB)
        AGG_SELF(accC, nidC)
        AGG_SELF(accD, nidD)
    }
    int r0a = rowptr[nidA], r1a = rowptr[nidA + 1];
    int r0b = rowptr[nidB], r1b = rowptr[nidB + 1];
    int r0c = rowptr[nidC], r1c = rowptr[nidC + 1];
    int r0d = rowptr[nidD], r1d = rowptr[nidD + 1];
    int basea = r0a, baseb = r0b, basec = r0c, based = r0d;
#pragma unroll 1
    while (basea < r1a || baseb < r1b || basec < r1c || based < r1d) {
        int ma = r1a - basea; ma = (ma < 0) ? 0 : ((ma > 64) ? 64 : ma);
        int mb = r1b - baseb; mb = (mb < 0) ? 0 : ((mb > 64) ? 64 : mb);
        int mc = r1c - basec; mc = (mc < 0) ? 0 : ((mc > 64) ? 64 : mc);
        int md = r1d - based; md = (md < 0) ? 0 : ((md > 64) ? 64 : md);
        int idxa = (lane < ma) ? csrc[basea + lane] : 0;
        int idxb = (lane < mb) ? csrc[baseb + lane] : 0;
        int idxc = (lane < mc) ? csrc[basec + lane] : 0;
        int idxd = (lane < md) ? csrc[based + lane] : 0;
        int m01 = (ma > mb) ? ma : mb;
        int m23 = (mc > md) ? mc : md;
        int mmax = (m01 > m23) ? m01 : m23;
        int nIter = (mmax + 3) >> 2;              // wave-uniform
#pragma unroll 2
        for (int it = 0; it < nIter; ++it) {
            int j = g + 4 * it;                   // j <= 63 always
            int sa = __shfl(idxa, j, 64);         // full EXEC here
            int sb = __shfl(idxb, j, 64);
            int sc = __shfl(idxc, j, 64);
            int sd = __shfl(idxd, j, 64);
            if (j < ma) AGG_ADD(accA, sa)
            if (j < mb) AGG_ADD(accB, sb)
            if (j < mc) AGG_ADD(accC, sc)
            if (j < md) AGG_ADD(accD, sd)
        }
        basea += 64; baseb += 64; basec += 64; based += 64;
    }
    AGG_REDUCE(accA, hA, dnA)
    AGG_REDUCE(accB, hB, dnB)
    AGG_REDUCE(accC, hC, dnC)
    AGG_REDUCE(accD, hD, dnD)
}

// layer-1 agg with fused layer-2 GEMM epilogue: T2 = (h1 @ W2) * dinv, h1 in regs only
__global__ __launch_bounds__(256) void k_agg_l1(const float* __restrict__ T,
                                                const int* __restrict__ rowptr,
                                                const int* __restrict__ csrc,
                                                const float* __restrict__ dinv,
                                                const float* __restrict__ bias,
                                                const float* __restrict__ W2,
                                                float* __restrict__ T2,
                                                int n, int npw) {
    int lane = threadIdx.x & 63;
    int w = threadIdx.x >> 6;
    int g = lane >> 4, c4 = lane & 15;
    float4 b4 = ((const float4*)bias)[c4];
    int gw = blockIdx.x * 4 + w;
    int n0 = gw * npw;
    int n1 = n0 + npw; if (n1 > n) n1 = n;
    if (n0 >= n1) return;
    int last = n1 - 1;
#pragma unroll 1
    for (int nid = n0; nid < n1; nid += 4) {
        int nidB = (nid + 1 <= last) ? nid + 1 : last;
        int nidC = (nid + 2 <= last) ? nid + 2 : last;
        int nidD = (nid + 3 <= last) ? nid + 3 : last;
        float dnA = dinv[nid], dnB = dinv[nidB];
        float dnC = dinv[nidC], dnD = dinv[nidD];
        float4 hA, hB, hC, hD;
        agg_gather4(T, rowptr, csrc, dnA, dnB, dnC, dnD, b4,
                    nid, nidB, nidC, nidD, g, c4, lane, hA, hB, hC, hD);
        float accA = 0.f, accB = 0.f, accC = 0.f, accD = 0.f;
#pragma unroll 4
        for (int q = 0; q < 16; ++q) {
            float w0 = W2[(4 * q + 0) * 64 + lane];
            float w1 = W2[(4 * q + 1) * 64 + lane];
            float w2v = W2[(4 * q + 2) * 64 + lane];
            float w3 = W2[(4 * q + 3) * 64 + lane];
            accA = fmaf(rlanef(hA.x, q), w0, accA);
            accA = fmaf(rlanef(hA.y, q), w1, accA);
            accA = fmaf(rlanef(hA.z, q), w2v, accA);
            accA = fmaf(rlanef(hA.w, q), w3, accA);
            accB = fmaf(rlanef(hB.x, q), w0, accB);
            accB = fmaf(rlanef(hB.y, q), w1, accB);
            accB = fmaf(rlanef(hB.z, q), w2v, accB);
            accB = fmaf(rlanef(hB.w, q), w3, accB);
            accC = fmaf(rlanef(hC.x, q), w0, accC);
            accC = fmaf(rlanef(hC.y, q), w1, accC);
            accC = fmaf(rlanef(hC.z, q), w2v, accC);
            accC = fmaf(rlanef(hC.w, q), w3, accC);
            accD = fmaf(rlanef(hD.x, q), w0, accD);
            accD = fmaf(rlanef(hD.y, q), w1, accD);
            accD = fmaf(rlanef(hD.z, q), w2v, accD);
            accD = fmaf(rlanef(hD.w, q), w3, accD);
        }
        T2[(size_t)nid * 64 + lane] = accA * dnA;
        T2[(size_t)nidB * 64 + lane] = accB * dnB;
        T2[(size_t)nidC * 64 + lane] = accC * dnC;
        T2[(size_t)nidD * 64 + lane] = accD * dnD;
    }
}

// layer-2 agg with fused uv GEMM epilogue:
// ut = h2 @ Wm1[0:64], vt = h2 @ Wm1[64:128] + bm1  (h2 in regs only)
__global__ __launch_bounds__(256) void k_agg_l2uv(const float* __restrict__ T,
                                                  const int* __restrict__ rowptr,
                                                  const int* __restrict__ csrc,
                                                  const float* __restrict__ dinv,
                                                  const float* __restrict__ bias,
                                                  const float* __restrict__ Wm1,
                                                  const float* __restrict__ bm1,
                                                  float* __restrict__ ut,
                                                  float* __restrict__ vt,
                                                  int n, int npw) {
    int lane = threadIdx.x & 63;
    int w = threadIdx.x >> 6;
    int g = lane >> 4, c4 = lane & 15;
    float4 b4 = ((const float4*)bias)[c4];
    float bv = bm1[lane];
    int gw = blockIdx.x * 4 + w;
    int n0 = gw * npw;
    int n1 = n0 + npw; if (n1 > n) n1 = n;
    if (n0 >= n1) return;
    int last = n1 - 1;
#pragma unroll 1
    for (int nid = n0; nid < n1; nid += 4) {
        int nidB = (nid + 1 <= last) ? nid + 1 : last;
        int nidC = (nid + 2 <= last) ? nid + 2 : last;
        int nidD = (nid + 3 <= last) ? nid + 3 : last;
        float dnA = dinv[nid], dnB = dinv[nidB];
        float dnC = dinv[nidC], dnD = dinv[nidD];
        float4 hA, hB, hC, hD;
        agg_gather4(T, rowptr, csrc, dnA, dnB, dnC, dnD, b4,
                    nid, nidB, nidC, nidD, g, c4, lane, hA, hB, hC, hD);
        // epilogue in two pair-passes to cap the live register set
        float auA = 0.f, avA = 0.f, auB = 0.f, avB = 0.f;
#pragma unroll 4
        for (int q = 0; q < 16; ++q) {
            float hA0 = rlanef(hA.x, q), hA1 = rlanef(hA.y, q);
            float hA2 = rlanef(hA.z, q), hA3 = rlanef(hA.w, q);
            float hB0 = rlanef(hB.x, q), hB1 = rlanef(hB.y, q);
            float hB2 = rlanef(hB.z, q), hB3 = rlanef(hB.w, q);
            float wu0 = Wm1[(4 * q + 0) * 64 + lane];
            float wu1 = Wm1[(4 * q + 1) * 64 + lane];
            float wu2 = Wm1[(4 * q + 2) * 64 + lane];
            float wu3 = Wm1[(4 * q + 3) * 64 + lane];
            float wv0 = Wm1[(64 + 4 * q + 0) * 64 + lane];
            float wv1 = Wm1[(64 + 4 * q + 1) * 64 + lane];
            float wv2 = Wm1[(64 + 4 * q + 2) * 64 + lane];
            float wv3 = Wm1[(64 + 4 * q + 3) * 64 + lane];
            auA = fmaf(hA0, wu0, auA); auA = fmaf(hA1, wu1, auA);
            auA = fmaf(hA2, wu2, auA); auA = fmaf(hA3, wu3, auA);
            avA = fmaf(hA0, wv0, avA); avA = fmaf(hA1, wv1, avA);
            avA = fmaf(hA2, wv2, avA); avA = fmaf(hA3, wv3, avA);
            auB = fmaf(hB0, wu0, auB); auB = fmaf(hB1, wu1, auB);
            auB = fmaf(hB2, wu2, auB); auB = fmaf(hB3, wu3, auB);
            avB = fmaf(hB0, wv0, avB); avB = fmaf(hB1, wv1, avB);
            avB = fmaf(hB2, wv2, avB); avB = fmaf(hB3, wv3, avB);
        }
        ut[(size_t)nid * 64 + lane] = auA;
        vt[(size_t)nid * 64 + lane] = avA + bv;
        ut[(size_t)nidB * 64 + lane] = auB;
        vt[(size_t)nidB * 64 + lane] = avB + bv;
        float auC = 0.f, avC = 0.f, auD = 0.f, avD = 0.f;
#pragma unroll 4
        for (int q = 0; q < 16; ++q) {
            float hC0 = rlanef(hC.x, q), hC1 = rlanef(hC.y, q);
            float hC2 = rlanef(hC.z, q), hC3 = rlanef(hC.w, q);
            float hD0 = rlanef(hD.x, q), hD1 = rlanef(hD.y, q);
            float hD2 = rlanef(hD.z, q), hD3 = rlanef(hD.w, q);
            float wu0 = Wm1[(4 * q + 0) * 64 + lane];
            float wu1 = Wm1[(4 * q + 1) * 64 + lane];
            float wu2 = Wm1[(4 * q + 2) * 64 + lane];
            float wu3 = Wm1[(4 * q + 3) * 64 + lane];
            float wv0 = Wm1[(64 + 4 * q + 0) * 64 + lane];
            float wv1 = Wm1[(64 + 4 * q + 1) * 64 + lane];
            float wv2 = Wm1[(64 + 4 * q + 2) * 64 + lane];
            float wv3 = Wm1[(64 + 4 * q + 3) * 64 + lane];
            auC = fmaf(hC0, wu0, auC); auC = fmaf(hC1, wu1, auC);
            auC = fmaf(hC2, wu2, auC); auC = fmaf(hC3, wu3, auC);
            avC = fmaf(hC0, wv0, avC); avC = fmaf(hC1, wv1, avC);
            avC = fmaf(hC2, wv2, avC); avC = fmaf(hC3, wv3, avC);
            auD = fmaf(hD0, wu0, auD); auD = fmaf(hD1, wu1, auD);
            auD = fmaf(hD2, wu2, auD); auD = fmaf(hD3, wu3, auD);
            avD = fmaf(hD0, wv0, avD); avD = fmaf(hD1, wv1, avD);
            avD = fmaf(hD2, wv2, avD); avD = fmaf(hD3, wv3, avD);
        }
        ut[(size_t)nidC * 64 + lane] = auC;
        vt[(size_t)nidC * 64 + lane] = avC + bv;
        ut[(size_t)nidD * 64 + lane] = auD;
        vt[(size_t)nidD * 64 + lane] = avD + bv;
    }
}

// ---------------- edge MLP (CSR order, u/v precomputed) ----------------

#define RELUADD4(zq, uq, vq) \
    zq.x = fmaxf(uq.x + vq.x, 0.f); zq.y = fmaxf(uq.y + vq.y, 0.f); \
    zq.z = fmaxf(uq.z + vq.z, 0.f); zq.w = fmaxf(uq.w + vq.w, 0.f);

#define S2Q(zs, j) { \
    const float* w2 = Wm2 + (size_t)(j) * 16; \
    o0.x = fmaf(zs, w2[0],  o0.x);  o0.y = fmaf(zs, w2[1],  o0.y); \
    o0.z = fmaf(zs, w2[2],  o0.z);  o0.w = fmaf(zs, w2[3],  o0.w); \
    o1.x = fmaf(zs, w2[4],  o1.x);  o1.y = fmaf(zs, w2[5],  o1.y); \
    o1.z = fmaf(zs, w2[6],  o1.z);  o1.w = fmaf(zs, w2[7],  o1.w); \
    o2.x = fmaf(zs, w2[8],  o2.x);  o2.y = fmaf(zs, w2[9],  o2.y); \
    o2.z = fmaf(zs, w2[10], o2.z);  o2.w = fmaf(zs, w2[11], o2.w); \
    o3.x = fmaf(zs, w2[12], o3.x);  o3.y = fmaf(zs, w2[13], o3.y); \
    o3.z = fmaf(zs, w2[14], o3.z);  o3.w = fmaf(zs, w2[15], o3.w); }

__global__ __launch_bounds__(256, 4) void k_mlp(const float* __restrict__ ut,
                                                const float* __restrict__ vt,
                                                const int* __restrict__ csrc,
                                                const int2* __restrict__ cde,
                                                const float* __restrict__ Wm2,  // [64][16]
                                                const float* __restrict__ bm2,
                                                float* __restrict__ out,
                                                int e) {
    int p = blockIdx.x * 256 + threadIdx.x;
    bool ok = p < e;
    int idx = ok ? p : 0;
    int r = csrc[idx];
    int2 cv = cde[idx];
    int c  = cv.x;
    int eo = cv.y;

    const float4* uq = (const float4*)(ut + (size_t)r * 64);
    const float4* vq = (const float4*)(vt + (size_t)c * 64);

    float4 u0 = uq[0],  u1 = uq[1],  u2 = uq[2],  u3 = uq[3];
    float4 u4 = uq[4],  u5 = uq[5],  u6 = uq[6],  u7 = uq[7];
    float4 u8 = uq[8],  u9 = uq[9],  u10 = uq[10], u11 = uq[11];
    float4 u12 = uq[12], u13 = uq[13], u14 = uq[14], u15 = uq[15];
    float4 v0 = vq[0],  v1 = vq[1],  v2 = vq[2],  v3 = vq[3];
    float4 v4 = vq[4],  v5 = vq[5],  v6 = vq[6],  v7 = vq[7];
    float4 v8 = vq[8],  v9 = vq[9],  v10 = vq[10], v11 = vq[11];
    float4 v12 = vq[12], v13 = vq[13], v14 = vq[14], v15 = vq[15];

    float4 z0, z1, z2, z3, z4, z5, z6, z7, z8, z9, z10, z11, z12, z13, z14, z15;
    RELUADD4(z0, u0, v0)    RELUADD4(z1, u1, v1)    RELUADD4(z2, u2, v2)    RELUADD4(z3, u3, v3)
    RELUADD4(z4, u4, v4)    RELUADD4(z5, u5, v5)    RELUADD4(z6, u6, v6)    RELUADD4(z7, u7, v7)
    RELUADD4(z8, u8, v8)    RELUADD4(z9, u9, v9)    RELUADD4(z10, u10, v10) RELUADD4(z11, u11, v11)
    RELUADD4(z12, u12, v12) RELUADD4(z13, u13, v13) RELUADD4(z14, u14, v14) RELUADD4(z15, u15, v15)

    const float4* b2q = (const float4*)bm2;
    float4 o0 = b2q[0], o1 = b2q[1], o2 = b2q[2], o3 = b2q[3];

    S2Q(z0.x, 0)   S2Q(z0.y, 1)   S2Q(z0.z, 2)   S2Q(z0.w, 3)
    S2Q(z1.x, 4)   S2Q(z1.y, 5)   S2Q(z1.z, 6)   S2Q(z1.w, 7)
    S2Q(z2.x, 8)   S2Q(z2.y, 9)   S2Q(z2.z, 10)  S2Q(z2.w, 11)
    S2Q(z3.x, 12)  S2Q(z3.y, 13)  S2Q(z3.z, 14)  S2Q(z3.w, 15)
    S2Q(z4.x, 16)  S2Q(z4.y, 17)  S2Q(z4.z, 18)  S2Q(z4.w, 19)
    S2Q(z5.x, 20)  S2Q(z5.y, 21)  S2Q(z5.z, 22)  S2Q(z5.w, 23)
    S2Q(z6.x, 24)  S2Q(z6.y, 25)  S2Q(z6.z, 26)  S2Q(z6.w, 27)
    S2Q(z7.x, 28)  S2Q(z7.y, 29)  S2Q(z7.z, 30)  S2Q(z7.w, 31)
    S2Q(z8.x, 32)  S2Q(z8.y, 33)  S2Q(z8.z, 34)  S2Q(z8.w, 35)
    S2Q(z9.x, 36)  S2Q(z9.y, 37)  S2Q(z9.z, 38)  S2Q(z9.w, 39)
    S2Q(z10.x, 40) S2Q(z10.y, 41) S2Q(z10.z, 42) S2Q(z10.w, 43)
    S2Q(z11.x, 44) S2Q(z11.y, 45) S2Q(z11.z, 46) S2Q(z11.w, 47)
    S2Q(z12.x, 48) S2Q(z12.y, 49) S2Q(z12.z, 50) S2Q(z12.w, 51)
    S2Q(z13.x, 52) S2Q(z13.y, 53) S2Q(z13.z, 54) S2Q(z13.w, 55)
    S2Q(z14.x, 56) S2Q(z14.y, 57) S2Q(z14.z, 58) S2Q(z14.w, 59)
    S2Q(z15.x, 60) S2Q(z15.y, 61) S2Q(z15.z, 62) S2Q(z15.w, 63)

    if (ok) {
        float4* op = (float4*)(out + (size_t)eo * 16);
        op[0] = o0; op[1] = o1; op[2] = o2; op[3] = o3;
    }
}

// ---------------- launch ----------------

extern "C" void kernel_launch(void* const* d_in, const int* in_sizes, int n_in,
                              void* d_out, int out_size, void* d_ws, size_t ws_size,
                              hipStream_t stream) {
    const float* x   = (const float*)d_in[0];
    const int*   ei  = (const int*)d_in[1];
    const float* W1  = (const float*)d_in[2];
    const float* b1  = (const float*)d_in[3];
    const float* W2  = (const float*)d_in[4];
    const float* b2  = (const float*)d_in[5];
    const float* Wm1 = (const float*)d_in[6];
    const float* bm1 = (const float*)d_in[7];
    const float* Wm2 = (const float*)d_in[8];
    const float* bm2 = (const float*)d_in[9];
    float* out = (float*)d_out;

    int n = in_sizes[0] / IN_C;       // 50000
    int e = in_sizes[1] / 2;          // 800000

    // workspace layout (16B-aligned chunks)
    char* w = (char*)d_ws;
    int* cnt    = (int*)w;                 w += (size_t)n * 4;
    int* tmp    = (int*)w;                 w += (size_t)n * 4;
    int* bsum   = (int*)w;                 w += 256 * 4;
    int* rowptr = (int*)w;                 w += (size_t)(n + 4) * 4;
    int* cur    = (int*)w;                 w += (size_t)n * 4;
    float* dinv = (float*)w;               w += (size_t)n * 4;
    int* csrc   = (int*)w;                 w += (size_t)e * 4;
    int2* cde   = (int2*)w;                w += (size_t)e * 8;
    float* t1   = (float*)w;               w += (size_t)n * HID * 4;
    float* t2   = (float*)w;               w += (size_t)n * HID * 4;
    float* vt   = (float*)w;               w += (size_t)n * HID * 4;
    float* ut   = t1;   // reuse: t1 dead after agg_l1 (agg_l2uv reads only t2)

    int nb_e256 = (e + 255) / 256;
    int nb_n256 = (n + 255) / 256;
    int nb_scan = (n + 1023) / 1024;

    hipMemsetAsync(cnt, 0, (size_t)n * 4, stream);
    k_count<<<nb_e256, 256, 0, stream>>>(ei, cnt, e);
    k_scan1<<<nb_scan, 1024, 0, stream>>>(cnt, tmp, bsum, n);
    k_scan2<<<1, 64, 0, stream>>>(bsum, nb_scan);
    k_scan3<<<nb_n256, 256, 0, stream>>>(cnt, tmp, bsum, rowptr, cur, dinv, n, e);
    k_scatter<<<nb_e256, 256, 0, stream>>>(ei, cur, csrc, cde, e);

    const int NPW = 8;                               // nodes per wave (gemm)
    int nwaves = (n + NPW - 1) / NPW;
    int nb_gemm = (nwaves + 3) / 4;
    const int NPB = 4;                               // nodes per wave (agg)
    int nb_agg = (n + 4 * NPB - 1) / (4 * NPB);

    // layer 1 transform
    k_gemm_node<IN_C><<<nb_gemm, 256, 0, stream>>>(x, W1, dinv, t1, n, NPW);
    // layer-1 agg + fused layer-2 transform
    k_agg_l1<<<nb_agg, 256, 0, stream>>>(t1, rowptr, csrc, dinv, b1, W2, t2, n, NPB);
    // layer-2 agg + fused uv transform (h2 never materialized)
    k_agg_l2uv<<<nb_agg, 256, 0, stream>>>(t2, rowptr, csrc, dinv, b2, Wm1, bm1,
                                           ut, vt, n, NPB);
    // edge MLP in CSR order
    int nb_mlp = (e + 255) / 256;
    k_mlp<<<nb_mlp, 256, 0, stream>>>(ut, vt, csrc, cde, Wm2, bm2, out, e);
}

// Round 15
// 291.359 us; speedup vs baseline: 1.0497x; 1.0497x over previous
//
#include <hip/hip_runtime.h>
#include <hip/hip_bf16.h>

// EdgePredictorGNN: 2-layer GCN + edge MLP.
// N=50000 nodes, in_c=128, hid=64, out_c=16, E=800000 edges.
// Round-15: revert to the round-13 PAIR-pipelined agg (quad regressed
// 292.5->305.8: nIter=max(4 degrees) wastes predicated slots + epilogue
// split). Keep hipMemsetAsync for cnt. Pair depth is the measured optimum.

#define IN_C 128
#define HID 64
#define OUT_C 16

__device__ __forceinline__ float rlanef(float v, int l) {
    return __uint_as_float(__builtin_amdgcn_readlane(__float_as_uint(v), l));
}

// ---------------- CSR build ----------------

__global__ void k_count(const int* __restrict__ ei, int* __restrict__ cnt, int e) {
    int i = blockIdx.x * blockDim.x + threadIdx.x;
    if (i < e) atomicAdd(&cnt[ei[e + i]], 1);   // dst = ei[1][i]
}

__global__ __launch_bounds__(1024) void k_scan1(const int* __restrict__ cnt,
                                                int* __restrict__ tmp,
                                                int* __restrict__ bsum, int n) {
    __shared__ int s[1024];
    int i = blockIdx.x * 1024 + threadIdx.x;
    int v = (i < n) ? cnt[i] : 0;
    s[threadIdx.x] = v;
    __syncthreads();
    for (int off = 1; off < 1024; off <<= 1) {
        int add = (threadIdx.x >= off) ? s[threadIdx.x - off] : 0;
        __syncthreads();
        s[threadIdx.x] += add;
        __syncthreads();
    }
    if (i < n) tmp[i] = s[threadIdx.x];
    if (threadIdx.x == 1023) bsum[blockIdx.x] = s[1023];
}

// wave-parallel exclusive scan of up to 64 block sums
__global__ __launch_bounds__(64) void k_scan2(int* __restrict__ bsum, int nb) {
    int lane = threadIdx.x;
    int v = (lane < nb) ? bsum[lane] : 0;
    int orig = v;
    for (int off = 1; off < 64; off <<= 1) {
        int t = __shfl_up(v, off, 64);
        if (lane >= off) v += t;
    }
    if (lane < nb) bsum[lane] = v - orig;   // exclusive prefix
}

__global__ void k_scan3(const int* __restrict__ cnt, const int* __restrict__ tmp,
                        const int* __restrict__ bsum, int* __restrict__ rowptr,
                        int* __restrict__ cur, float* __restrict__ dinv, int n, int e) {
    int i = blockIdx.x * blockDim.x + threadIdx.x;
    if (i < n) {
        int excl = tmp[i] - cnt[i] + bsum[i >> 10];
        rowptr[i] = excl;
        cur[i] = excl;
        dinv[i] = 1.0f / sqrtf((float)(cnt[i] + 1));  // +1 self loop
        if (i == 0) rowptr[n] = e;
    }
}

__global__ void k_scatter(const int* __restrict__ ei, int* __restrict__ cur,
                          int* __restrict__ csrc, int2* __restrict__ cde, int e) {
    int i = blockIdx.x * blockDim.x + threadIdx.x;
    if (i < e) {
        int s = ei[i];
        int d = ei[e + i];
        int p = atomicAdd(&cur[d], 1);
        csrc[p] = s;
        cde[p] = make_int2(d, i);
    }
}

// ---------------- node GEMM: T = (A @ W) * dinv[row]  (W is [K,64]) ----------------

template <int K>
__global__ __launch_bounds__(256) void k_gemm_node(const float* __restrict__ A,
                                                   const float* __restrict__ W,
                                                   const float* __restrict__ dinv,
                                                   float* __restrict__ T,
                                                   int n, int npw) {
    int lane = threadIdx.x & 63;
    int w = threadIdx.x >> 6;
    float wr[K];
#pragma unroll
    for (int k = 0; k < K; ++k) wr[k] = W[k * 64 + lane];
    int gw = blockIdx.x * 4 + w;
    int n0 = gw * npw;
    int n1 = n0 + npw; if (n1 > n) n1 = n;
#pragma unroll 1
    for (int i = n0; i < n1; ++i) {
        float a0 = A[(size_t)i * K + lane];
        float a1 = 0.f;
        if (K == 128) a1 = A[(size_t)i * K + 64 + lane];
        float acc = 0.f;
#pragma unroll
        for (int k = 0; k < 64; ++k) acc = fmaf(rlanef(a0, k), wr[k], acc);
        if (K == 128) {
#pragma unroll
            for (int k = 0; k < 64; ++k) acc = fmaf(rlanef(a1, k), wr[64 + k], acc);
        }
        T[(size_t)i * 64 + lane] = acc * dinv[i];
    }
}

// ---------------- GCN aggregation, PAIR-pipelined gather core ----------------
// lane = (g = lane>>4, c4 = lane&15). Two nodes (A,B) gathered concurrently:
// both index preloads issue together; the row loop interleaves A/B loads
// (independent chains, 8 rows in flight per iter). Trip counts wave-uniform;
// __shfl always executed with full EXEC; only the adds are predicated.

__device__ __forceinline__ void agg_gather2(const float* __restrict__ T,
                                            const int* __restrict__ rowptr,
                                            const int* __restrict__ csrc,
                                            float dnA, float dnB, float4 b4,
                                            int nidA, int nidB,
                                            int g, int c4, int lane,
                                            float4& hA, float4& hB) {
    float4 accA = make_float4(0.f, 0.f, 0.f, 0.f);
    float4 accB = make_float4(0.f, 0.f, 0.f, 0.f);
    if (g == 0) {
        accA = *(const float4*)(T + (size_t)nidA * 64 + 4 * c4);   // self loop A
        accB = *(const float4*)(T + (size_t)nidB * 64 + 4 * c4);   // self loop B
    }
    int r0a = rowptr[nidA], r1a = rowptr[nidA + 1];
    int r0b = rowptr[nidB], r1b = rowptr[nidB + 1];
    int basea = r0a, baseb = r0b;
#pragma unroll 1
    while (basea < r1a || baseb < r1b) {
        int ma = r1a - basea; ma = (ma < 0) ? 0 : ((ma > 64) ? 64 : ma);
        int mb = r1b - baseb; mb = (mb < 0) ? 0 : ((mb > 64) ? 64 : mb);
        int idxa = (lane < ma) ? csrc[basea + lane] : 0;
        int idxb = (lane < mb) ? csrc[baseb + lane] : 0;
        int mmax = (ma > mb) ? ma : mb;
        int nIter = (mmax + 3) >> 2;              // wave-uniform
#pragma unroll 2
        for (int it = 0; it < nIter; ++it) {
            int j = g + 4 * it;                   // j <= 63 always
            int sa = __shfl(idxa, j, 64);         // full EXEC here
            int sb = __shfl(idxb, j, 64);
            if (j < ma) {
                float4 t = *(const float4*)(T + (size_t)sa * 64 + 4 * c4);
                accA.x += t.x; accA.y += t.y; accA.z += t.z; accA.w += t.w;
            }
            if (j < mb) {
                float4 t = *(const float4*)(T + (size_t)sb * 64 + 4 * c4);
                accB.x += t.x; accB.y += t.y; accB.z += t.z; accB.w += t.w;
            }
        }
        basea += 64; baseb += 64;
    }
    accA.x += __shfl_xor(accA.x, 16, 64); accA.y += __shfl_xor(accA.y, 16, 64);
    accA.z += __shfl_xor(accA.z, 16, 64); accA.w += __shfl_xor(accA.w, 16, 64);
    accB.x += __shfl_xor(accB.x, 16, 64); accB.y += __shfl_xor(accB.y, 16, 64);
    accB.z += __shfl_xor(accB.z, 16, 64); accB.w += __shfl_xor(accB.w, 16, 64);
    accA.x += __shfl_xor(accA.x, 32, 64); accA.y += __shfl_xor(accA.y, 32, 64);
    accA.z += __shfl_xor(accA.z, 32, 64); accA.w += __shfl_xor(accA.w, 32, 64);
    accB.x += __shfl_xor(accB.x, 32, 64); accB.y += __shfl_xor(accB.y, 32, 64);
    accB.z += __shfl_xor(accB.z, 32, 64); accB.w += __shfl_xor(accB.w, 32, 64);
    hA.x = fmaxf(fmaf(dnA, accA.x, b4.x), 0.f);
    hA.y = fmaxf(fmaf(dnA, accA.y, b4.y), 0.f);
    hA.z = fmaxf(fmaf(dnA, accA.z, b4.z), 0.f);
    hA.w = fmaxf(fmaf(dnA, accA.w, b4.w), 0.f);
    hB.x = fmaxf(fmaf(dnB, accB.x, b4.x), 0.f);
    hB.y = fmaxf(fmaf(dnB, accB.y, b4.y), 0.f);
    hB.z = fmaxf(fmaf(dnB, accB.z, b4.z), 0.f);
    hB.w = fmaxf(fmaf(dnB, accB.w, b4.w), 0.f);
}

// layer-1 agg with fused layer-2 GEMM epilogue: T2 = (h1 @ W2) * dinv, h1 in regs only
__global__ __launch_bounds__(256) void k_agg_l1(const float* __restrict__ T,
                                                const int* __restrict__ rowptr,
                                                const int* __restrict__ csrc,
                                                const float* __restrict__ dinv,
                                                const float* __restrict__ bias,
                                                const float* __restrict__ W2,
                                                float* __restrict__ T2,
                                                int n, int npw) {
    int lane = threadIdx.x & 63;
    int w = threadIdx.x >> 6;
    int g = lane >> 4, c4 = lane & 15;
    float4 b4 = ((const float4*)bias)[c4];
    int gw = blockIdx.x * 4 + w;
    int n0 = gw * npw;
    int n1 = n0 + npw; if (n1 > n) n1 = n;
#pragma unroll 1
    for (int nid = n0; nid < n1; nid += 2) {
        int nidB = (nid + 1 < n1) ? nid + 1 : nid;
        float dnA = dinv[nid], dnB = dinv[nidB];
        float4 hA, hB;
        agg_gather2(T, rowptr, csrc, dnA, dnB, b4, nid, nidB, g, c4, lane, hA, hB);
        float accA = 0.f, accB = 0.f;
#pragma unroll 4
        for (int q = 0; q < 16; ++q) {
            float w0 = W2[(4 * q + 0) * 64 + lane];
            float w1 = W2[(4 * q + 1) * 64 + lane];
            float w2v = W2[(4 * q + 2) * 64 + lane];
            float w3 = W2[(4 * q + 3) * 64 + lane];
            accA = fmaf(rlanef(hA.x, q), w0, accA);
            accA = fmaf(rlanef(hA.y, q), w1, accA);
            accA = fmaf(rlanef(hA.z, q), w2v, accA);
            accA = fmaf(rlanef(hA.w, q), w3, accA);
            accB = fmaf(rlanef(hB.x, q), w0, accB);
            accB = fmaf(rlanef(hB.y, q), w1, accB);
            accB = fmaf(rlanef(hB.z, q), w2v, accB);
            accB = fmaf(rlanef(hB.w, q), w3, accB);
        }
        T2[(size_t)nid * 64 + lane] = accA * dnA;
        T2[(size_t)nidB * 64 + lane] = accB * dnB;
    }
}

// layer-2 agg with fused uv GEMM epilogue:
// ut = h2 @ Wm1[0:64], vt = h2 @ Wm1[64:128] + bm1  (h2 in regs only)
__global__ __launch_bounds__(256) void k_agg_l2uv(const float* __restrict__ T,
                                                  const int* __restrict__ rowptr,
                                                  const int* __restrict__ csrc,
                                                  const float* __restrict__ dinv,
                                                  const float* __restrict__ bias,
                                                  const float* __restrict__ Wm1,
                                                  const float* __restrict__ bm1,
                                                  float* __restrict__ ut,
                                                  float* __restrict__ vt,
                                                  int n, int npw) {
    int lane = threadIdx.x & 63;
    int w = threadIdx.x >> 6;
    int g = lane >> 4, c4 = lane & 15;
    float4 b4 = ((const float4*)bias)[c4];
    float bv = bm1[lane];
    int gw = blockIdx.x * 4 + w;
    int n0 = gw * npw;
    int n1 = n0 + npw; if (n1 > n) n1 = n;
#pragma unroll 1
    for (int nid = n0; nid < n1; nid += 2) {
        int nidB = (nid + 1 < n1) ? nid + 1 : nid;
        float dnA = dinv[nid], dnB = dinv[nidB];
        float4 hA, hB;
        agg_gather2(T, rowptr, csrc, dnA, dnB, b4, nid, nidB, g, c4, lane, hA, hB);
        float auA = 0.f, avA = 0.f, auB = 0.f, avB = 0.f;
#pragma unroll 4
        for (int q = 0; q < 16; ++q) {
            float hA0 = rlanef(hA.x, q), hA1 = rlanef(hA.y, q);
            float hA2 = rlanef(hA.z, q), hA3 = rlanef(hA.w, q);
            float hB0 = rlanef(hB.x, q), hB1 = rlanef(hB.y, q);
            float hB2 = rlanef(hB.z, q), hB3 = rlanef(hB.w, q);
            float wu0 = Wm1[(4 * q + 0) * 64 + lane];
            float wu1 = Wm1[(4 * q + 1) * 64 + lane];
            float wu2 = Wm1[(4 * q + 2) * 64 + lane];
            float wu3 = Wm1[(4 * q + 3) * 64 + lane];
            float wv0 = Wm1[(64 + 4 * q + 0) * 64 + lane];
            float wv1 = Wm1[(64 + 4 * q + 1) * 64 + lane];
            float wv2 = Wm1[(64 + 4 * q + 2) * 64 + lane];
            float wv3 = Wm1[(64 + 4 * q + 3) * 64 + lane];
            auA = fmaf(hA0, wu0, auA); auA = fmaf(hA1, wu1, auA);
            auA = fmaf(hA2, wu2, auA); auA = fmaf(hA3, wu3, auA);
            avA = fmaf(hA0, wv0, avA); avA = fmaf(hA1, wv1, avA);
            avA = fmaf(hA2, wv2, avA); avA = fmaf(hA3, wv3, avA);
            auB = fmaf(hB0, wu0, auB); auB = fmaf(hB1, wu1, auB);
            auB = fmaf(hB2, wu2, auB); auB = fmaf(hB3, wu3, auB);
            avB = fmaf(hB0, wv0, avB); avB = fmaf(hB1, wv1, avB);
            avB = fmaf(hB2, wv2, avB); avB = fmaf(hB3, wv3, avB);
        }
        ut[(size_t)nid * 64 + lane] = auA;
        vt[(size_t)nid * 64 + lane] = avA + bv;
        ut[(size_t)nidB * 64 + lane] = auB;
        vt[(size_t)nidB * 64 + lane] = avB + bv;
    }
}

// ---------------- edge MLP (CSR order, u/v precomputed) ----------------

#define RELUADD4(zq, uq, vq) \
    zq.x = fmaxf(uq.x + vq.x, 0.f); zq.y = fmaxf(uq.y + vq.y, 0.f); \
    zq.z = fmaxf(uq.z + vq.z, 0.f); zq.w = fmaxf(uq.w + vq.w, 0.f);

#define S2Q(zs, j) { \
    const float* w2 = Wm2 + (size_t)(j) * 16; \
    o0.x = fmaf(zs, w2[0],  o0.x);  o0.y = fmaf(zs, w2[1],  o0.y); \
    o0.z = fmaf(zs, w2[2],  o0.z);  o0.w = fmaf(zs, w2[3],  o0.w); \
    o1.x = fmaf(zs, w2[4],  o1.x);  o1.y = fmaf(zs, w2[5],  o1.y); \
    o1.z = fmaf(zs, w2[6],  o1.z);  o1.w = fmaf(zs, w2[7],  o1.w); \
    o2.x = fmaf(zs, w2[8],  o2.x);  o2.y = fmaf(zs, w2[9],  o2.y); \
    o2.z = fmaf(zs, w2[10], o2.z);  o2.w = fmaf(zs, w2[11], o2.w); \
    o3.x = fmaf(zs, w2[12], o3.x);  o3.y = fmaf(zs, w2[13], o3.y); \
    o3.z = fmaf(zs, w2[14], o3.z);  o3.w = fmaf(zs, w2[15], o3.w); }

__global__ __launch_bounds__(256, 4) void k_mlp(const float* __restrict__ ut,
                                                const float* __restrict__ vt,
                                                const int* __restrict__ csrc,
                                                const int2* __restrict__ cde,
                                                const float* __restrict__ Wm2,  // [64][16]
                                                const float* __restrict__ bm2,
                                                float* __restrict__ out,
                                                int e) {
    int p = blockIdx.x * 256 + threadIdx.x;
    bool ok = p < e;
    int idx = ok ? p : 0;
    int r = csrc[idx];
    int2 cv = cde[idx];
    int c  = cv.x;
    int eo = cv.y;

    const float4* uq = (const float4*)(ut + (size_t)r * 64);
    const float4* vq = (const float4*)(vt + (size_t)c * 64);

    float4 u0 = uq[0],  u1 = uq[1],  u2 = uq[2],  u3 = uq[3];
    float4 u4 = uq[4],  u5 = uq[5],  u6 = uq[6],  u7 = uq[7];
    float4 u8 = uq[8],  u9 = uq[9],  u10 = uq[10], u11 = uq[11];
    float4 u12 = uq[12], u13 = uq[13], u14 = uq[14], u15 = uq[15];
    float4 v0 = vq[0],  v1 = vq[1],  v2 = vq[2],  v3 = vq[3];
    float4 v4 = vq[4],  v5 = vq[5],  v6 = vq[6],  v7 = vq[7];
    float4 v8 = vq[8],  v9 = vq[9],  v10 = vq[10], v11 = vq[11];
    float4 v12 = vq[12], v13 = vq[13], v14 = vq[14], v15 = vq[15];

    float4 z0, z1, z2, z3, z4, z5, z6, z7, z8, z9, z10, z11, z12, z13, z14, z15;
    RELUADD4(z0, u0, v0)    RELUADD4(z1, u1, v1)    RELUADD4(z2, u2, v2)    RELUADD4(z3, u3, v3)
    RELUADD4(z4, u4, v4)    RELUADD4(z5, u5, v5)    RELUADD4(z6, u6, v6)    RELUADD4(z7, u7, v7)
    RELUADD4(z8, u8, v8)    RELUADD4(z9, u9, v9)    RELUADD4(z10, u10, v10) RELUADD4(z11, u11, v11)
    RELUADD4(z12, u12, v12) RELUADD4(z13, u13, v13) RELUADD4(z14, u14, v14) RELUADD4(z15, u15, v15)

    const float4* b2q = (const float4*)bm2;
    float4 o0 = b2q[0], o1 = b2q[1], o2 = b2q[2], o3 = b2q[3];

    S2Q(z0.x, 0)   S2Q(z0.y, 1)   S2Q(z0.z, 2)   S2Q(z0.w, 3)
    S2Q(z1.x, 4)   S2Q(z1.y, 5)   S2Q(z1.z, 6)   S2Q(z1.w, 7)
    S2Q(z2.x, 8)   S2Q(z2.y, 9)   S2Q(z2.z, 10)  S2Q(z2.w, 11)
    S2Q(z3.x, 12)  S2Q(z3.y, 13)  S2Q(z3.z, 14)  S2Q(z3.w, 15)
    S2Q(z4.x, 16)  S2Q(z4.y, 17)  S2Q(z4.z, 18)  S2Q(z4.w, 19)
    S2Q(z5.x, 20)  S2Q(z5.y, 21)  S2Q(z5.z, 22)  S2Q(z5.w, 23)
    S2Q(z6.x, 24)  S2Q(z6.y, 25)  S2Q(z6.z, 26)  S2Q(z6.w, 27)
    S2Q(z7.x, 28)  S2Q(z7.y, 29)  S2Q(z7.z, 30)  S2Q(z7.w, 31)
    S2Q(z8.x, 32)  S2Q(z8.y, 33)  S2Q(z8.z, 34)  S2Q(z8.w, 35)
    S2Q(z9.x, 36)  S2Q(z9.y, 37)  S2Q(z9.z, 38)  S2Q(z9.w, 39)
    S2Q(z10.x, 40) S2Q(z10.y, 41) S2Q(z10.z, 42) S2Q(z10.w, 43)
    S2Q(z11.x, 44) S2Q(z11.y, 45) S2Q(z11.z, 46) S2Q(z11.w, 47)
    S2Q(z12.x, 48) S2Q(z12.y, 49) S2Q(z12.z, 50) S2Q(z12.w, 51)
    S2Q(z13.x, 52) S2Q(z13.y, 53) S2Q(z13.z, 54) S2Q(z13.w, 55)
    S2Q(z14.x, 56) S2Q(z14.y, 57) S2Q(z14.z, 58) S2Q(z14.w, 59)
    S2Q(z15.x, 60) S2Q(z15.y, 61) S2Q(z15.z, 62) S2Q(z15.w, 63)

    if (ok) {
        float4* op = (float4*)(out + (size_t)eo * 16);
        op[0] = o0; op[1] = o1; op[2] = o2; op[3] = o3;
    }
}

// ---------------- launch ----------------

extern "C" void kernel_launch(void* const* d_in, const int* in_sizes, int n_in,
                              void* d_out, int out_size, void* d_ws, size_t ws_size,
                              hipStream_t stream) {
    const float* x   = (const float*)d_in[0];
    const int*   ei  = (const int*)d_in[1];
    const float* W1  = (const float*)d_in[2];
    const float* b1  = (const float*)d_in[3];
    const float* W2  = (const float*)d_in[4];
    const float* b2  = (const float*)d_in[5];
    const float* Wm1 = (const float*)d_in[6];
    const float* bm1 = (const float*)d_in[7];
    const float* Wm2 = (const float*)d_in[8];
    const float* bm2 = (const float*)d_in[9];
    float* out = (float*)d_out;

    int n = in_sizes[0] / IN_C;       // 50000
    int e = in_sizes[1] / 2;          // 800000

    // workspace layout (16B-aligned chunks)
    char* w = (char*)d_ws;
    int* cnt    = (int*)w;                 w += (size_t)n * 4;
    int* tmp    = (int*)w;                 w += (size_t)n * 4;
    int* bsum   = (int*)w;                 w += 256 * 4;
    int* rowptr = (int*)w;                 w += (size_t)(n + 4) * 4;
    int* cur    = (int*)w;                 w += (size_t)n * 4;
    float* dinv = (float*)w;               w += (size_t)n * 4;
    int* csrc   = (int*)w;                 w += (size_t)e * 4;
    int2* cde   = (int2*)w;                w += (size_t)e * 8;
    float* t1   = (float*)w;               w += (size_t)n * HID * 4;
    float* t2   = (float*)w;               w += (size_t)n * HID * 4;
    float* vt   = (float*)w;               w += (size_t)n * HID * 4;
    float* ut   = t1;   // reuse: t1 dead after agg_l1 (agg_l2uv reads only t2)

    int nb_e256 = (e + 255) / 256;
    int nb_n256 = (n + 255) / 256;
    int nb_scan = (n + 1023) / 1024;

    hipMemsetAsync(cnt, 0, (size_t)n * 4, stream);
    k_count<<<nb_e256, 256, 0, stream>>>(ei, cnt, e);
    k_scan1<<<nb_scan, 1024, 0, stream>>>(cnt, tmp, bsum, n);
    k_scan2<<<1, 64, 0, stream>>>(bsum, nb_scan);
    k_scan3<<<nb_n256, 256, 0, stream>>>(cnt, tmp, bsum, rowptr, cur, dinv, n, e);
    k_scatter<<<nb_e256, 256, 0, stream>>>(ei, cur, csrc, cde, e);

    const int NPW = 8;                               // nodes per wave (gemm)
    int nwaves = (n + NPW - 1) / NPW;
    int nb_gemm = (nwaves + 3) / 4;
    const int NPB = 4;                               // nodes per wave (agg)
    int nb_agg = (n + 4 * NPB - 1) / (4 * NPB);

    // layer 1 transform
    k_gemm_node<IN_C><<<nb_gemm, 256, 0, stream>>>(x, W1, dinv, t1, n, NPW);
    // layer-1 agg + fused layer-2 transform
    k_agg_l1<<<nb_agg, 256, 0, stream>>>(t1, rowptr, csrc, dinv, b1, W2, t2, n, NPB);
    // layer-2 agg + fused uv transform (h2 never materialized)
    k_agg_l2uv<<<nb_agg, 256, 0, stream>>>(t2, rowptr, csrc, dinv, b2, Wm1, bm1,
                                           ut, vt, n, NPB);
    // edge MLP in CSR order
    int nb_mlp = (e + 255) / 256;
    k_mlp<<<nb_mlp, 256, 0, stream>>>(ut, vt, csrc, cde, Wm2, bm2, out, e);
}